// Round 5
// baseline (622.310 us; speedup 1.0000x reference)
//
#include <hip/hip_runtime.h>

// Problem constants (from reference)
#define NPIX   786432                      // C*H*W = 3*512*512
#define NSP    55050                       // noise pixels per sample
#define BATCH  64
#define BPS    32                          // copy blocks per sample
#define F4_PER_SAMPLE (NPIX / 4)           // 196608 float4s
#define F4_PER_BLOCK  (F4_PER_SAMPLE / BPS) // 6144 float4s (98304 B, full lines)
#define F4_PER_THREAD (F4_PER_BLOCK / 256)  // 24

typedef float f32x4 __attribute__((ext_vector_type(4)));

#define CLIP4(v) \
    v.x = fminf(fmaxf(v.x, 0.f), 1.f); v.y = fminf(fmaxf(v.y, 0.f), 1.f); \
    v.z = fminf(fmaxf(v.z, 0.f), 1.f); v.w = fminf(fmaxf(v.w, 0.f), 1.f);

// One kernel: 32 blocks copy each sample's 3.1 MB slice; the LAST block to
// finish a sample (agent-scope ACQ_REL ticket) immediately scatters that
// sample's noise. Scatter overlaps with other samples' copies; no spinning,
// so any block schedule is deadlock-free. Release publishes copy stores
// across XCDs before the ticket; acquire invalidates stale lines on the
// scatter block's XCD before its write-allocate stores (WAW-safe).
__global__ __launch_bounds__(256) void fused_pipeline(
    const f32x4* __restrict__ in, f32x4* __restrict__ out,
    const int* __restrict__ indices, const int* __restrict__ num_salt,
    int* __restrict__ counters)
{
    const int b  = blockIdx.y;
    const int cb = blockIdx.x;
    const int t  = threadIdx.x;
    const size_t base = (size_t)b * F4_PER_SAMPLE + (size_t)cb * F4_PER_BLOCK;
    const f32x4* __restrict__ ip = in + base;
    f32x4* __restrict__ op = out + base;

    // copy+clip this block's contiguous 6144-float4 chunk, 4-wide batches
    #pragma unroll
    for (int kk = 0; kk < F4_PER_THREAD; kk += 4) {
        f32x4 v0 = __builtin_nontemporal_load(ip + (kk + 0) * 256 + t);
        f32x4 v1 = __builtin_nontemporal_load(ip + (kk + 1) * 256 + t);
        f32x4 v2 = __builtin_nontemporal_load(ip + (kk + 2) * 256 + t);
        f32x4 v3 = __builtin_nontemporal_load(ip + (kk + 3) * 256 + t);
        CLIP4(v0) CLIP4(v1) CLIP4(v2) CLIP4(v3)
        op[(kk + 0) * 256 + t] = v0;
        op[(kk + 1) * 256 + t] = v1;
        op[(kk + 2) * 256 + t] = v2;
        op[(kk + 3) * 256 + t] = v3;
    }

    __shared__ int last;
    __syncthreads();   // all block stores issued & complete to L2
    if (t == 0) {
        int ticket = __hip_atomic_fetch_add(&counters[b], 1,
                        __ATOMIC_ACQ_REL, __HIP_MEMORY_SCOPE_AGENT);
        last = (ticket == BPS - 1);
    }
    __syncthreads();
    if (!last) return;

    // this sample's copy is fully published -> scatter its noise
    const int* __restrict__ ind = indices + b * NSP;
    float* __restrict__ o = (float*)out + (size_t)b * NPIX;
    const int ns = num_salt[b];
    #pragma unroll 4
    for (int j = t; j < NSP; j += 256)
        o[ind[j]] = (j < ns) ? 1.0f : 0.0f;
}

// ---- fallback (ws too small for counters): proven two-pass path ----
__global__ __launch_bounds__(256) void copy_clip_kernel(
    const f32x4* __restrict__ in, f32x4* __restrict__ out, int n4) {
    int stride = gridDim.x * blockDim.x;
    for (int i = blockIdx.x * blockDim.x + threadIdx.x; i < n4; i += stride) {
        f32x4 v = __builtin_nontemporal_load(in + i);
        CLIP4(v)
        out[i] = v;
    }
}
__global__ __launch_bounds__(256) void scatter_kernel(
    const int* __restrict__ indices, const int* __restrict__ num_salt,
    float* __restrict__ out) {
    int b = blockIdx.y;
    int j = blockIdx.x * blockDim.x + threadIdx.x;
    if (j >= NSP) return;
    out[(size_t)b * NPIX + indices[b * NSP + j]] = (j < num_salt[b]) ? 1.0f : 0.0f;
}

extern "C" void kernel_launch(void* const* d_in, const int* in_sizes, int n_in,
                              void* d_out, int out_size, void* d_ws, size_t ws_size,
                              hipStream_t stream) {
    const float* x        = (const float*)d_in[0];
    const int*   indices  = (const int*)d_in[1];
    const int*   num_salt = (const int*)d_in[2];
    float*       out      = (float*)d_out;

    if (ws_size >= BATCH * sizeof(int)) {
        int* counters = (int*)d_ws;
        hipMemsetAsync(counters, 0, BATCH * sizeof(int), stream);
        dim3 grid(BPS, BATCH);   // 2048 blocks
        fused_pipeline<<<grid, 256, 0, stream>>>(
            (const f32x4*)x, (f32x4*)out, indices, num_salt, counters);
    } else {
        int n4 = out_size / 4;
        copy_clip_kernel<<<2048, 256, 0, stream>>>((const f32x4*)x, (f32x4*)out, n4);
        dim3 sgrid((NSP + 255) / 256, BATCH);
        scatter_kernel<<<sgrid, 256, 0, stream>>>(indices, num_salt, out);
    }
}

// Round 6
// 154.027 us; speedup vs baseline: 4.0403x; 4.0403x over previous
//
#include <hip/hip_runtime.h>

// Problem constants (from reference)
#define NPIX   786432                       // C*H*W = 3*512*512
#define NSP    55050                        // noise pixels per sample
#define BATCH  64
#define BPS    16                           // blocks per sample
#define PIX_PER_BLOCK (NPIX / BPS)          // 49152 pixels (192 KB)
#define F4_PER_BLOCK  (PIX_PER_BLOCK / 4)   // 12288 float4
#define F4_PER_THREAD (F4_PER_BLOCK / 256)  // 48
#define MASK_WORDS    (PIX_PER_BLOCK / 16)  // 3072 u32 = 12 KB LDS (2 bits/px)

typedef float f32x4 __attribute__((ext_vector_type(4)));

// Single kernel, no inter-block sync, no global scatter:
//  phase 1: scan this sample's 55050 indices, keep those inside this block's
//           contiguous pixel chunk, set 2-bit codes in an LDS mask
//           (bit0 = noise, bit1 = salt). Indices are a randperm prefix ->
//           unique pixels -> disjoint bit-pairs -> LDS atomicOr deterministic.
//  phase 2: one fully-coalesced streaming pass: NT load, clip, mask-substitute,
//           NT store (output never re-read on device -> keep L2/L3 clean for
//           the index array).
__global__ __launch_bounds__(256) void fused_mask_kernel(
    const f32x4* __restrict__ in, f32x4* __restrict__ out,
    const int* __restrict__ indices, const int* __restrict__ num_salt)
{
    __shared__ unsigned int smask[MASK_WORDS];
    const int b  = blockIdx.y;
    const int cb = blockIdx.x;
    const int t  = threadIdx.x;

    // zero the mask
    #pragma unroll
    for (int w = t; w < MASK_WORDS; w += 256) smask[w] = 0u;
    __syncthreads();

    // phase 1: filter-scan indices into the LDS mask
    const int lo = cb * PIX_PER_BLOCK;
    const int ns = num_salt[b];
    const int* __restrict__ ind = indices + b * NSP;
    #pragma unroll 4
    for (int j = t; j < NSP; j += 256) {
        int lp = ind[j] - lo;                       // coalesced index load
        if ((unsigned)lp < (unsigned)PIX_PER_BLOCK) {
            unsigned bits = (1u | ((j < ns) ? 2u : 0u)) << ((lp & 15) * 2);
            atomicOr(&smask[lp >> 4], bits);        // rare (~13/wave-iter total)
        }
    }
    __syncthreads();

    // phase 2: streaming copy + clip + mask apply
    const size_t base4 = (size_t)b * (NPIX / 4) + (size_t)cb * F4_PER_BLOCK;
    const f32x4* __restrict__ ip = in + base4;
    f32x4* __restrict__ op = out + base4;
    #pragma unroll 4
    for (int kk = 0; kk < F4_PER_THREAD; ++kk) {
        int i = kk * 256 + t;
        f32x4 v = __builtin_nontemporal_load(ip + i);
        // mask byte for float4 i: word i>>2, byte (i&3). 4-lane same-word
        // reads broadcast (free); 16 distinct banks -> conflict-free.
        unsigned m = (smask[i >> 2] >> ((i & 3) * 8)) & 0xFFu;
        f32x4 o;
        o.x = (m & 1u)   ? (float)((m >> 1) & 1u) : fminf(fmaxf(v.x, 0.f), 1.f);
        o.y = (m & 4u)   ? (float)((m >> 3) & 1u) : fminf(fmaxf(v.y, 0.f), 1.f);
        o.z = (m & 16u)  ? (float)((m >> 5) & 1u) : fminf(fmaxf(v.z, 0.f), 1.f);
        o.w = (m & 64u)  ? (float)((m >> 7) & 1u) : fminf(fmaxf(v.w, 0.f), 1.f);
        __builtin_nontemporal_store(o, op + i);
    }
}

extern "C" void kernel_launch(void* const* d_in, const int* in_sizes, int n_in,
                              void* d_out, int out_size, void* d_ws, size_t ws_size,
                              hipStream_t stream) {
    const float* x        = (const float*)d_in[0];
    const int*   indices  = (const int*)d_in[1];
    const int*   num_salt = (const int*)d_in[2];
    float*       out      = (float*)d_out;

    dim3 grid(BPS, BATCH);   // (16, 64) = 1024 blocks, 4 per CU
    fused_mask_kernel<<<grid, 256, 0, stream>>>(
        (const f32x4*)x, (f32x4*)out, indices, num_salt);
}

// Round 7
// 104.878 us; speedup vs baseline: 5.9336x; 1.4686x over previous
//
#include <hip/hip_runtime.h>

// Problem constants (from reference)
#define NPIX    786432                      // C*H*W = 3*512*512
#define NSP     55050                       // noise pixels per sample
#define BATCH   64
#define CHUNK_PX 32768                      // pixels per bucket/chunk
#define NCHUNK  (NPIX / CHUNK_PX)           // 24 chunks per sample
#define CAP     2816                        // bucket capacity (mean 2294, +11 sigma)
#define F4_PER_CHUNK (CHUNK_PX / 4)         // 8192 float4
#define MASK_WORDS   (CHUNK_PX / 16)        // 2048 u32 = 8 KB LDS (2 bits/px)

// ws layout: u32 gcount[64*24] @ 0 (6144 B, zeroed per call);
//            u16 entries[64*24*CAP] @ 8192 (8.65 MB)
#define ENTRIES_OFF 8192
#define WS_NEEDED   (ENTRIES_OFF + (size_t)BATCH * NCHUNK * CAP * 2)

typedef float f32x4 __attribute__((ext_vector_type(4)));
typedef unsigned int u32;
typedef unsigned short u16;

// Kernel A: bin each sample's indices into 24 per-chunk buckets.
// 16 blocks per sample scan disjoint strided subsets (14 iters each).
// Entry order within a bucket is schedule-dependent, but the SET of entries
// is deterministic and kernel B applies them order-independently.
__global__ __launch_bounds__(256) void bin_kernel(
    const int* __restrict__ indices, const int* __restrict__ num_salt,
    u32* __restrict__ gcount, u16* __restrict__ entries)
{
    __shared__ u32 hist[NCHUNK];
    __shared__ u32 basev[NCHUNK];
    const int b = blockIdx.y;
    const int t = threadIdx.x;
    const int ns = num_salt[b];
    const int* __restrict__ ind = indices + b * NSP;
    const int start = blockIdx.x * 256 + t;      // stride 16*256 = 4096

    if (t < NCHUNK) hist[t] = 0;
    __syncthreads();
    for (int j = start; j < NSP; j += 4096)      // scan 1: count
        atomicAdd(&hist[ind[j] >> 15], 1u);
    __syncthreads();
    if (t < NCHUNK) {
        basev[t] = atomicAdd(&gcount[b * NCHUNK + t], hist[t]);  // reserve
        hist[t] = 0;
    }
    __syncthreads();
    for (int j = start; j < NSP; j += 4096) {    // scan 2: append (L2-hot)
        int p = ind[j];
        int q = p >> 15;
        u32 r = basev[q] + atomicAdd(&hist[q], 1u);
        u16 e = (u16)((p & 32767) | ((j < ns) ? 32768u : 0u));
        if (r < CAP) entries[(b * NCHUNK + q) * CAP + r] = e;
    }
}

// Kernel B: per 32768-px chunk: read own bucket (~2294 entries, 9 iters),
// build 8 KB LDS 2-bit mask (disjoint-bit atomicOr -> deterministic),
// then one fully-coalesced NT-load/NT-store streaming pass.
__global__ __launch_bounds__(256) void apply_kernel(
    const f32x4* __restrict__ in, f32x4* __restrict__ out,
    const u32* __restrict__ gcount, const u16* __restrict__ entries)
{
    __shared__ u32 smask[MASK_WORDS];
    const int b = blockIdx.y, q = blockIdx.x, t = threadIdx.x;

    #pragma unroll
    for (int w = t; w < MASK_WORDS; w += 256) smask[w] = 0u;
    __syncthreads();

    u32 cnt = gcount[b * NCHUNK + q];
    if (cnt > CAP) cnt = CAP;
    const u16* __restrict__ ep = entries + (b * NCHUNK + q) * CAP;
    for (u32 e = t; e < cnt; e += 256) {
        u32 v = ep[e];
        u32 lp = v & 32767u;
        u32 bits = (1u | ((v >> 15) << 1)) << ((lp & 15) * 2);
        atomicOr(&smask[lp >> 4], bits);
    }
    __syncthreads();

    const size_t base4 = (size_t)(b * NCHUNK + q) * F4_PER_CHUNK;
    const f32x4* __restrict__ ip = in + base4;
    f32x4* __restrict__ op = out + base4;
    #pragma unroll 4
    for (int kk = 0; kk < F4_PER_CHUNK / 256; ++kk) {
        int i = kk * 256 + t;
        f32x4 v = __builtin_nontemporal_load(ip + i);
        u32 m = (smask[i >> 2] >> ((i & 3) * 8)) & 0xFFu;
        f32x4 o;
        o.x = (m & 1u)  ? (float)((m >> 1) & 1u) : fminf(fmaxf(v.x, 0.f), 1.f);
        o.y = (m & 4u)  ? (float)((m >> 3) & 1u) : fminf(fmaxf(v.y, 0.f), 1.f);
        o.z = (m & 16u) ? (float)((m >> 5) & 1u) : fminf(fmaxf(v.z, 0.f), 1.f);
        o.w = (m & 64u) ? (float)((m >> 7) & 1u) : fminf(fmaxf(v.w, 0.f), 1.f);
        __builtin_nontemporal_store(o, op + i);
    }
}

// ---- fallback (ws too small): proven round-2/4 two-pass path ----
__global__ __launch_bounds__(256) void copy_clip_kernel(
    const f32x4* __restrict__ in, f32x4* __restrict__ out, int n4) {
    int stride = gridDim.x * blockDim.x;
    for (int i = blockIdx.x * blockDim.x + threadIdx.x; i < n4; i += stride) {
        f32x4 v = __builtin_nontemporal_load(in + i);
        v.x = fminf(fmaxf(v.x, 0.f), 1.f); v.y = fminf(fmaxf(v.y, 0.f), 1.f);
        v.z = fminf(fmaxf(v.z, 0.f), 1.f); v.w = fminf(fmaxf(v.w, 0.f), 1.f);
        out[i] = v;
    }
}
__global__ __launch_bounds__(256) void scatter_kernel(
    const int* __restrict__ indices, const int* __restrict__ num_salt,
    float* __restrict__ out) {
    int b = blockIdx.y;
    int j = blockIdx.x * blockDim.x + threadIdx.x;
    if (j >= NSP) return;
    out[(size_t)b * NPIX + indices[b * NSP + j]] = (j < num_salt[b]) ? 1.0f : 0.0f;
}

extern "C" void kernel_launch(void* const* d_in, const int* in_sizes, int n_in,
                              void* d_out, int out_size, void* d_ws, size_t ws_size,
                              hipStream_t stream) {
    const float* x        = (const float*)d_in[0];
    const int*   indices  = (const int*)d_in[1];
    const int*   num_salt = (const int*)d_in[2];
    float*       out      = (float*)d_out;

    if (ws_size >= WS_NEEDED) {
        u32* gcount  = (u32*)d_ws;
        u16* entries = (u16*)((char*)d_ws + ENTRIES_OFF);
        hipMemsetAsync(gcount, 0, BATCH * NCHUNK * sizeof(u32), stream);
        dim3 agrid(16, BATCH);                 // 1024 blocks
        bin_kernel<<<agrid, 256, 0, stream>>>(indices, num_salt, gcount, entries);
        dim3 bgrid(NCHUNK, BATCH);             // 1536 blocks, ~6/CU
        apply_kernel<<<bgrid, 256, 0, stream>>>(
            (const f32x4*)x, (f32x4*)out, gcount, entries);
    } else {
        int n4 = out_size / 4;
        copy_clip_kernel<<<2048, 256, 0, stream>>>((const f32x4*)x, (f32x4*)out, n4);
        dim3 sgrid((NSP + 255) / 256, BATCH);
        scatter_kernel<<<sgrid, 256, 0, stream>>>(indices, num_salt, out);
    }
}

// Round 8
// 98.693 us; speedup vs baseline: 6.3055x; 1.0627x over previous
//
#include <hip/hip_runtime.h>

// Problem constants (from reference)
#define NPIX     786432                     // C*H*W = 3*512*512
#define NSP      55050                      // noise pixels per sample
#define BATCH    64
#define LOG_CHUNK 14
#define CHUNK_PX (1 << LOG_CHUNK)           // 16384 pixels per chunk
#define NCHUNK   (NPIX / CHUNK_PX)          // 48 chunks per sample
#define BINB     8                          // bin blocks per sample
#define CAP_B    224                        // entries per (sample,chunk,binblock) slice
                                            // mean 143.4, +6.8 sigma; inputs fixed
#define F4_PER_CHUNK (CHUNK_PX / 4)         // 4096 float4
#define MASK_WORDS   (CHUNK_PX / 16)        // 1024 u32 = 4 KB LDS (2 bits/px)

// ws layout: u32 counts[64][48][8] @ 0 (98304 B, fully rewritten every call);
//            u16 entries[64][48][8][CAP_B] @ 98304 (11.0 MB)
#define COUNTS_WORDS (BATCH * NCHUNK * BINB)
#define ENTRIES_OFF  (COUNTS_WORDS * 4)
#define WS_NEEDED    (ENTRIES_OFF + (size_t)BATCH * NCHUNK * BINB * CAP_B * 2)

typedef float f32x4 __attribute__((ext_vector_type(4)));
typedef unsigned int u32;
typedef unsigned short u16;

// Kernel A: single-scan bin. 8 blocks per sample scan disjoint strided halves
// of the index list (int2-vectorized, NT — indices are read exactly once),
// stage entries per-chunk in LDS (LDS atomicAdd only), then dump each chunk
// list to its OWN global slice + count. No global atomics, no memset.
// Entry order within a slice is schedule-dependent; the SET is deterministic
// and kernel B ORs disjoint bits -> order-independent result.
__global__ __launch_bounds__(512) void bin_kernel(
    const int* __restrict__ indices, const int* __restrict__ num_salt,
    u32* __restrict__ counts, u16* __restrict__ entries)
{
    __shared__ u16 stage[NCHUNK][CAP_B];
    __shared__ u32 lcnt[NCHUNK];
    const int b  = blockIdx.y;
    const int cb = blockIdx.x;
    const int t  = threadIdx.x;
    const int ns = num_salt[b];

    if (t < NCHUNK) lcnt[t] = 0;
    __syncthreads();

    // scan: int2 m covers j = 2m, 2m+1.  M = NSP/2 = 27525 int2s.
    typedef int i32x2 __attribute__((ext_vector_type(2)));
    const i32x2* __restrict__ ind2 = (const i32x2*)(indices + b * NSP);
    const int M = NSP / 2;
    for (int m = cb * 512 + t; m < M; m += BINB * 512) {
        i32x2 p2 = __builtin_nontemporal_load(ind2 + m);
        #pragma unroll
        for (int h = 0; h < 2; ++h) {
            int p = p2[h];
            int j = 2 * m + h;
            int q = p >> LOG_CHUNK;
            u32 r = atomicAdd(&lcnt[q], 1u);
            u16 e = (u16)((p & (CHUNK_PX - 1)) | ((j < ns) ? 0x8000u : 0u));
            if (r < CAP_B) stage[q][r] = e;
        }
    }
    __syncthreads();

    // dump: each chunk's LDS list -> dedicated global slice (coalesced u16)
    for (int q = 0; q < NCHUNK; ++q) {
        u32 c = lcnt[q]; if (c > CAP_B) c = CAP_B;
        if (t == 0) counts[(b * NCHUNK + q) * BINB + cb] = c;
        u16* __restrict__ dst = entries + ((size_t)(b * NCHUNK + q) * BINB + cb) * CAP_B;
        for (u32 e = t; e < c; e += 512) dst[e] = stage[q][e];
    }
}

// Kernel B: per 16384-px chunk: read 8 slices (~143 entries each), build 4 KB
// LDS 2-bit mask (disjoint-bit atomicOr -> deterministic), then one
// fully-coalesced NT-load/NT-store streaming pass.
__global__ __launch_bounds__(256) void apply_kernel(
    const f32x4* __restrict__ in, f32x4* __restrict__ out,
    const u32* __restrict__ counts, const u16* __restrict__ entries)
{
    __shared__ u32 smask[MASK_WORDS];
    const int b = blockIdx.y, q = blockIdx.x, t = threadIdx.x;

    #pragma unroll
    for (int w = t; w < MASK_WORDS; w += 256) smask[w] = 0u;
    __syncthreads();

    const u32* __restrict__ cp = counts + (b * NCHUNK + q) * BINB;
    const u16* __restrict__ ep = entries + (size_t)(b * NCHUNK + q) * BINB * CAP_B;
    #pragma unroll
    for (int cb = 0; cb < BINB; ++cb) {
        u32 cnt = cp[cb];                          // uniform -> scalar load
        const u16* __restrict__ sl = ep + cb * CAP_B;
        for (u32 e = t; e < cnt; e += 256) {
            u32 v = sl[e];
            u32 lp = v & (CHUNK_PX - 1);
            u32 bits = (1u | ((v >> 15) << 1)) << ((lp & 15) * 2);
            atomicOr(&smask[lp >> 4], bits);
        }
    }
    __syncthreads();

    const size_t base4 = (size_t)(b * NCHUNK + q) * F4_PER_CHUNK;
    const f32x4* __restrict__ ip = in + base4;
    f32x4* __restrict__ op = out + base4;
    #pragma unroll 4
    for (int kk = 0; kk < F4_PER_CHUNK / 256; ++kk) {
        int i = kk * 256 + t;
        f32x4 v = __builtin_nontemporal_load(ip + i);
        u32 m = (smask[i >> 2] >> ((i & 3) * 8)) & 0xFFu;
        f32x4 o;
        o.x = (m & 1u)  ? (float)((m >> 1) & 1u) : fminf(fmaxf(v.x, 0.f), 1.f);
        o.y = (m & 4u)  ? (float)((m >> 3) & 1u) : fminf(fmaxf(v.y, 0.f), 1.f);
        o.z = (m & 16u) ? (float)((m >> 5) & 1u) : fminf(fmaxf(v.z, 0.f), 1.f);
        o.w = (m & 64u) ? (float)((m >> 7) & 1u) : fminf(fmaxf(v.w, 0.f), 1.f);
        __builtin_nontemporal_store(o, op + i);
    }
}

// ---- fallback (ws too small): proven round-2/4 two-pass path ----
__global__ __launch_bounds__(256) void copy_clip_kernel(
    const f32x4* __restrict__ in, f32x4* __restrict__ out, int n4) {
    int stride = gridDim.x * blockDim.x;
    for (int i = blockIdx.x * blockDim.x + threadIdx.x; i < n4; i += stride) {
        f32x4 v = __builtin_nontemporal_load(in + i);
        v.x = fminf(fmaxf(v.x, 0.f), 1.f); v.y = fminf(fmaxf(v.y, 0.f), 1.f);
        v.z = fminf(fmaxf(v.z, 0.f), 1.f); v.w = fminf(fmaxf(v.w, 0.f), 1.f);
        out[i] = v;
    }
}
__global__ __launch_bounds__(256) void scatter_kernel(
    const int* __restrict__ indices, const int* __restrict__ num_salt,
    float* __restrict__ out) {
    int b = blockIdx.y;
    int j = blockIdx.x * blockDim.x + threadIdx.x;
    if (j >= NSP) return;
    out[(size_t)b * NPIX + indices[b * NSP + j]] = (j < num_salt[b]) ? 1.0f : 0.0f;
}

extern "C" void kernel_launch(void* const* d_in, const int* in_sizes, int n_in,
                              void* d_out, int out_size, void* d_ws, size_t ws_size,
                              hipStream_t stream) {
    const float* x        = (const float*)d_in[0];
    const int*   indices  = (const int*)d_in[1];
    const int*   num_salt = (const int*)d_in[2];
    float*       out      = (float*)d_out;

    if (ws_size >= WS_NEEDED) {
        u32* counts  = (u32*)d_ws;
        u16* entries = (u16*)((char*)d_ws + ENTRIES_OFF);
        dim3 agrid(BINB, BATCH);               // (8, 64) = 512 blocks x 512 thr
        bin_kernel<<<agrid, 512, 0, stream>>>(indices, num_salt, counts, entries);
        dim3 bgrid(NCHUNK, BATCH);             // (48, 64) = 3072 blocks
        apply_kernel<<<bgrid, 256, 0, stream>>>(
            (const f32x4*)x, (f32x4*)out, counts, entries);
    } else {
        int n4 = out_size / 4;
        copy_clip_kernel<<<2048, 256, 0, stream>>>((const f32x4*)x, (f32x4*)out, n4);
        dim3 sgrid((NSP + 255) / 256, BATCH);
        scatter_kernel<<<sgrid, 256, 0, stream>>>(indices, num_salt, out);
    }
}

// Round 9
// 86.027 us; speedup vs baseline: 7.2339x; 1.1472x over previous
//
#include <hip/hip_runtime.h>

// Problem constants (from reference)
#define NPIX     786432                     // C*H*W = 3*512*512
#define NSP      55050                      // noise pixels per sample
#define BATCH    64
#define LOG_CHUNK 15
#define CHUNK_PX (1 << LOG_CHUNK)           // 32768 pixels per chunk
#define NCHUNK   (NPIX / CHUNK_PX)          // 24 chunks per sample
#define BINB     16                         // bin blocks per sample
#define CAP_B    224                        // entries per (sample,chunk,binblock)
                                            // mean 143.4, +6.7 sigma; inputs fixed
#define F4_PER_CHUNK (CHUNK_PX / 4)         // 8192 float4
#define MASK_WORDS   (CHUNK_PX / 16)        // 2048 u32 = 8 KB LDS (2 bits/px)

// ws layout: u32 counts[64][24][16] @ 0 (98304 B, fully rewritten every call);
//            u16 entries[64][24][16][CAP_B] @ 98304 (11.0 MB)
#define COUNTS_WORDS (BATCH * NCHUNK * BINB)
#define ENTRIES_OFF  (COUNTS_WORDS * 4)
#define WS_NEEDED    (ENTRIES_OFF + (size_t)BATCH * NCHUNK * BINB * CAP_B * 2)

typedef float f32x4 __attribute__((ext_vector_type(4)));
typedef int   i32x2 __attribute__((ext_vector_type(2)));
typedef unsigned int u32;
typedef unsigned short u16;

// Kernel A: single-scan bin, 16 blocks/sample (4/CU). int2 NT index loads
// (8 B alignment holds for every b; 16 B does not). LDS atomicAdd compaction
// into per-chunk staging lists, then a WAVE-PARALLEL dump: wave w dumps
// chunks w, w+8, w+16 concurrently. No global atomics, no memset.
// Entry order within a slice is schedule-dependent; the SET is deterministic
// and kernel B ORs disjoint bits -> order-independent result.
__global__ __launch_bounds__(512) void bin_kernel(
    const int* __restrict__ indices, const int* __restrict__ num_salt,
    u32* __restrict__ counts, u16* __restrict__ entries)
{
    __shared__ u16 stage[NCHUNK][CAP_B];
    __shared__ u32 lcnt[NCHUNK];
    const int b  = blockIdx.y;
    const int cb = blockIdx.x;
    const int t  = threadIdx.x;
    const int ns = num_salt[b];

    if (t < NCHUNK) lcnt[t] = 0;
    __syncthreads();

    // scan: int2 m covers j = 2m, 2m+1.  M = NSP/2 = 27525 int2s (exact).
    const i32x2* __restrict__ ind2 = (const i32x2*)(indices + b * NSP);
    const int M = NSP / 2;
    for (int m = cb * 512 + t; m < M; m += BINB * 512) {
        i32x2 p2 = __builtin_nontemporal_load(ind2 + m);
        #pragma unroll
        for (int h = 0; h < 2; ++h) {          // two independent atomic chains
            int p = p2[h];
            int j = 2 * m + h;
            int q = p >> LOG_CHUNK;
            u32 r = atomicAdd(&lcnt[q], 1u);
            u16 e = (u16)((p & (CHUNK_PX - 1)) | ((j < ns) ? 0x8000u : 0u));
            if (r < CAP_B) stage[q][r] = e;
        }
    }
    __syncthreads();

    // wave-parallel dump: 8 waves x 3 chunks each
    const int w = t >> 6, lane = t & 63;
    for (int q = w; q < NCHUNK; q += 8) {
        u32 c = lcnt[q]; if (c > CAP_B) c = CAP_B;
        if (lane == 0) counts[(b * NCHUNK + q) * BINB + cb] = c;
        u16* __restrict__ dst = entries + ((size_t)(b * NCHUNK + q) * BINB + cb) * CAP_B;
        for (u32 e = lane; e < c; e += 64) dst[e] = stage[q][e];
    }
}

// Kernel B: per 32768-px chunk (512 threads): read 16 slices (~143 entries
// each), build 8 KB LDS 2-bit mask (disjoint-bit atomicOr -> deterministic),
// then one fully-coalesced streaming pass. NT loads (input read once, keep
// L3 clean); PLAIN stores (A/B vs prior NT stores — fillBuffer sustains
// 7 TB/s with allocating stores).
__global__ __launch_bounds__(512) void apply_kernel(
    const f32x4* __restrict__ in, f32x4* __restrict__ out,
    const u32* __restrict__ counts, const u16* __restrict__ entries)
{
    __shared__ u32 smask[MASK_WORDS];
    const int b = blockIdx.y, q = blockIdx.x, t = threadIdx.x;

    #pragma unroll
    for (int w = t; w < MASK_WORDS; w += 512) smask[w] = 0u;
    __syncthreads();

    const u32* __restrict__ cp = counts + (b * NCHUNK + q) * BINB;
    const u16* __restrict__ ep = entries + (size_t)(b * NCHUNK + q) * BINB * CAP_B;
    #pragma unroll
    for (int cb = 0; cb < BINB; ++cb) {
        u32 cnt = cp[cb];                      // uniform -> scalar
        const u16* __restrict__ sl = ep + cb * CAP_B;
        for (u32 e = t; e < cnt; e += 512) {
            u32 v = sl[e];
            u32 lp = v & (CHUNK_PX - 1);
            u32 bits = (1u | ((v >> 15) << 1)) << ((lp & 15) * 2);
            atomicOr(&smask[lp >> 4], bits);
        }
    }
    __syncthreads();

    const size_t base4 = (size_t)(b * NCHUNK + q) * F4_PER_CHUNK;
    const f32x4* __restrict__ ip = in + base4;
    f32x4* __restrict__ op = out + base4;
    #pragma unroll 4
    for (int kk = 0; kk < F4_PER_CHUNK / 512; ++kk) {
        int i = kk * 512 + t;
        f32x4 v = __builtin_nontemporal_load(ip + i);
        u32 m = (smask[i >> 2] >> ((i & 3) * 8)) & 0xFFu;
        f32x4 o;
        o.x = (m & 1u)  ? (float)((m >> 1) & 1u) : fminf(fmaxf(v.x, 0.f), 1.f);
        o.y = (m & 4u)  ? (float)((m >> 3) & 1u) : fminf(fmaxf(v.y, 0.f), 1.f);
        o.z = (m & 16u) ? (float)((m >> 5) & 1u) : fminf(fmaxf(v.z, 0.f), 1.f);
        o.w = (m & 64u) ? (float)((m >> 7) & 1u) : fminf(fmaxf(v.w, 0.f), 1.f);
        op[i] = o;
    }
}

// ---- fallback (ws too small): proven round-2/4 two-pass path ----
__global__ __launch_bounds__(256) void copy_clip_kernel(
    const f32x4* __restrict__ in, f32x4* __restrict__ out, int n4) {
    int stride = gridDim.x * blockDim.x;
    for (int i = blockIdx.x * blockDim.x + threadIdx.x; i < n4; i += stride) {
        f32x4 v = __builtin_nontemporal_load(in + i);
        v.x = fminf(fmaxf(v.x, 0.f), 1.f); v.y = fminf(fmaxf(v.y, 0.f), 1.f);
        v.z = fminf(fmaxf(v.z, 0.f), 1.f); v.w = fminf(fmaxf(v.w, 0.f), 1.f);
        out[i] = v;
    }
}
__global__ __launch_bounds__(256) void scatter_kernel(
    const int* __restrict__ indices, const int* __restrict__ num_salt,
    float* __restrict__ out) {
    int b = blockIdx.y;
    int j = blockIdx.x * blockDim.x + threadIdx.x;
    if (j >= NSP) return;
    out[(size_t)b * NPIX + indices[b * NSP + j]] = (j < num_salt[b]) ? 1.0f : 0.0f;
}

extern "C" void kernel_launch(void* const* d_in, const int* in_sizes, int n_in,
                              void* d_out, int out_size, void* d_ws, size_t ws_size,
                              hipStream_t stream) {
    const float* x        = (const float*)d_in[0];
    const int*   indices  = (const int*)d_in[1];
    const int*   num_salt = (const int*)d_in[2];
    float*       out      = (float*)d_out;

    if (ws_size >= WS_NEEDED) {
        u32* counts  = (u32*)d_ws;
        u16* entries = (u16*)((char*)d_ws + ENTRIES_OFF);
        dim3 agrid(BINB, BATCH);               // (16, 64) = 1024 blocks x 512 thr
        bin_kernel<<<agrid, 512, 0, stream>>>(indices, num_salt, counts, entries);
        dim3 bgrid(NCHUNK, BATCH);             // (24, 64) = 1536 blocks x 512 thr
        apply_kernel<<<bgrid, 512, 0, stream>>>(
            (const f32x4*)x, (f32x4*)out, counts, entries);
    } else {
        int n4 = out_size / 4;
        copy_clip_kernel<<<2048, 256, 0, stream>>>((const f32x4*)x, (f32x4*)out, n4);
        dim3 sgrid((NSP + 255) / 256, BATCH);
        scatter_kernel<<<sgrid, 256, 0, stream>>>(indices, num_salt, out);
    }
}

// Round 10
// 84.675 us; speedup vs baseline: 7.3494x; 1.0160x over previous
//
#include <hip/hip_runtime.h>

// Problem constants (from reference)
#define NPIX     786432                     // C*H*W = 3*512*512
#define NSP      55050                      // noise pixels per sample
#define BATCH    64
#define LOG_CHUNK 15
#define CHUNK_PX (1 << LOG_CHUNK)           // 32768 pixels per chunk
#define NCHUNK   (NPIX / CHUNK_PX)          // 24 chunks per sample
#define BINB     16                         // bin blocks per sample
#define CAP_B    224                        // entries per (sample,chunk,binblock)
#define F4_PER_CHUNK (CHUNK_PX / 4)         // 8192 float4
#define MASK_WORDS   (CHUNK_PX / 16)        // 2048 u32 = 8 KB LDS (2 bits/px)
#define PF       8                          // prefetched stream iterations

// ws layout: u32 counts[64][24][16] @ 0 (fully rewritten every call);
//            u16 entries[64][24][16][CAP_B] @ 98304 (11.0 MB)
#define COUNTS_WORDS (BATCH * NCHUNK * BINB)
#define ENTRIES_OFF  (COUNTS_WORDS * 4)
#define WS_NEEDED    (ENTRIES_OFF + (size_t)BATCH * NCHUNK * BINB * CAP_B * 2)

typedef float f32x4 __attribute__((ext_vector_type(4)));
typedef int   i32x2 __attribute__((ext_vector_type(2)));
typedef unsigned int u32;
typedef unsigned short u16;

// Kernel A (unchanged from round 9 — proven ~5 µs): single-scan bin,
// 16 blocks/sample, int2 NT index loads, LDS atomicAdd compaction,
// wave-parallel dump to dedicated slices. No global atomics, no memset.
__global__ __launch_bounds__(512) void bin_kernel(
    const int* __restrict__ indices, const int* __restrict__ num_salt,
    u32* __restrict__ counts, u16* __restrict__ entries)
{
    __shared__ u16 stage[NCHUNK][CAP_B];
    __shared__ u32 lcnt[NCHUNK];
    const int b  = blockIdx.y;
    const int cb = blockIdx.x;
    const int t  = threadIdx.x;
    const int ns = num_salt[b];

    if (t < NCHUNK) lcnt[t] = 0;
    __syncthreads();

    const i32x2* __restrict__ ind2 = (const i32x2*)(indices + b * NSP);
    const int M = NSP / 2;                   // 27525 int2s (exact)
    for (int m = cb * 512 + t; m < M; m += BINB * 512) {
        i32x2 p2 = __builtin_nontemporal_load(ind2 + m);
        #pragma unroll
        for (int h = 0; h < 2; ++h) {
            int p = p2[h];
            int j = 2 * m + h;
            int q = p >> LOG_CHUNK;
            u32 r = atomicAdd(&lcnt[q], 1u);
            u16 e = (u16)((p & (CHUNK_PX - 1)) | ((j < ns) ? 0x8000u : 0u));
            if (r < CAP_B) stage[q][r] = e;
        }
    }
    __syncthreads();

    const int w = t >> 6, lane = t & 63;
    for (int q = w; q < NCHUNK; q += 8) {
        u32 c = lcnt[q]; if (c > CAP_B) c = CAP_B;
        if (lane == 0) counts[(b * NCHUNK + q) * BINB + cb] = c;
        u16* __restrict__ dst = entries + ((size_t)(b * NCHUNK + q) * BINB + cb) * CAP_B;
        for (u32 e = lane; e < c; e += 64) dst[e] = stage[q][e];
    }
}

#define DECODE_STORE(v, i)                                                     \
    {                                                                          \
        u32 m = (smask[(i) >> 2] >> (((i) & 3) * 8)) & 0xFFu;                  \
        f32x4 o;                                                               \
        o.x = (m & 1u)  ? (float)((m >> 1) & 1u) : fminf(fmaxf(v.x, 0.f), 1.f);\
        o.y = (m & 4u)  ? (float)((m >> 3) & 1u) : fminf(fmaxf(v.y, 0.f), 1.f);\
        o.z = (m & 16u) ? (float)((m >> 5) & 1u) : fminf(fmaxf(v.z, 0.f), 1.f);\
        o.w = (m & 64u) ? (float)((m >> 7) & 1u) : fminf(fmaxf(v.w, 0.f), 1.f);\
        op[i] = o;                                                             \
    }

// Kernel B: per 32768-px chunk (512 threads). T14 issue-early: the first PF=8
// stream NT loads are issued BEFORE the mask build, so their HBM latency
// hides under the entry reads + LDS atomicOr + barrier instead of after it.
__global__ __launch_bounds__(512) void apply_kernel(
    const f32x4* __restrict__ in, f32x4* __restrict__ out,
    const u32* __restrict__ counts, const u16* __restrict__ entries)
{
    __shared__ u32 smask[MASK_WORDS];
    const int b = blockIdx.y, q = blockIdx.x, t = threadIdx.x;

    const size_t base4 = (size_t)(b * NCHUNK + q) * F4_PER_CHUNK;
    const f32x4* __restrict__ ip = in + base4;
    f32x4* __restrict__ op = out + base4;

    // --- issue-early: first PF stream loads (independent of the mask) ---
    f32x4 pf[PF];
    #pragma unroll
    for (int k = 0; k < PF; ++k)
        pf[k] = __builtin_nontemporal_load(ip + k * 512 + t);

    // --- mask build (entry loads overlap the in-flight prefetches) ---
    #pragma unroll
    for (int w = t; w < MASK_WORDS; w += 512) smask[w] = 0u;
    __syncthreads();

    const u32* __restrict__ cp = counts + (b * NCHUNK + q) * BINB;
    const u16* __restrict__ ep = entries + (size_t)(b * NCHUNK + q) * BINB * CAP_B;
    #pragma unroll
    for (int cb = 0; cb < BINB; ++cb) {
        u32 cnt = cp[cb];                      // uniform -> scalar
        const u16* __restrict__ sl = ep + cb * CAP_B;
        for (u32 e = t; e < cnt; e += 512) {
            u32 v = sl[e];
            u32 lp = v & (CHUNK_PX - 1);
            u32 bits = (1u | ((v >> 15) << 1)) << ((lp & 15) * 2);
            atomicOr(&smask[lp >> 4], bits);
        }
    }
    __syncthreads();

    // --- drain prefetched iterations ---
    #pragma unroll
    for (int k = 0; k < PF; ++k)
        DECODE_STORE(pf[k], k * 512 + t)

    // --- remaining stream iterations ---
    #pragma unroll
    for (int kk = PF; kk < F4_PER_CHUNK / 512; ++kk) {
        int i = kk * 512 + t;
        f32x4 v = __builtin_nontemporal_load(ip + i);
        DECODE_STORE(v, i)
    }
}

// ---- fallback (ws too small): proven round-2/4 two-pass path ----
__global__ __launch_bounds__(256) void copy_clip_kernel(
    const f32x4* __restrict__ in, f32x4* __restrict__ out, int n4) {
    int stride = gridDim.x * blockDim.x;
    for (int i = blockIdx.x * blockDim.x + threadIdx.x; i < n4; i += stride) {
        f32x4 v = __builtin_nontemporal_load(in + i);
        v.x = fminf(fmaxf(v.x, 0.f), 1.f); v.y = fminf(fmaxf(v.y, 0.f), 1.f);
        v.z = fminf(fmaxf(v.z, 0.f), 1.f); v.w = fminf(fmaxf(v.w, 0.f), 1.f);
        out[i] = v;
    }
}
__global__ __launch_bounds__(256) void scatter_kernel(
    const int* __restrict__ indices, const int* __restrict__ num_salt,
    float* __restrict__ out) {
    int b = blockIdx.y;
    int j = blockIdx.x * blockDim.x + threadIdx.x;
    if (j >= NSP) return;
    out[(size_t)b * NPIX + indices[b * NSP + j]] = (j < num_salt[b]) ? 1.0f : 0.0f;
}

extern "C" void kernel_launch(void* const* d_in, const int* in_sizes, int n_in,
                              void* d_out, int out_size, void* d_ws, size_t ws_size,
                              hipStream_t stream) {
    const float* x        = (const float*)d_in[0];
    const int*   indices  = (const int*)d_in[1];
    const int*   num_salt = (const int*)d_in[2];
    float*       out      = (float*)d_out;

    if (ws_size >= WS_NEEDED) {
        u32* counts  = (u32*)d_ws;
        u16* entries = (u16*)((char*)d_ws + ENTRIES_OFF);
        dim3 agrid(BINB, BATCH);               // (16, 64) x 512 thr
        bin_kernel<<<agrid, 512, 0, stream>>>(indices, num_salt, counts, entries);
        dim3 bgrid(NCHUNK, BATCH);             // (24, 64) x 512 thr
        apply_kernel<<<bgrid, 512, 0, stream>>>(
            (const f32x4*)x, (f32x4*)out, counts, entries);
    } else {
        int n4 = out_size / 4;
        copy_clip_kernel<<<2048, 256, 0, stream>>>((const f32x4*)x, (f32x4*)out, n4);
        dim3 sgrid((NSP + 255) / 256, BATCH);
        scatter_kernel<<<sgrid, 256, 0, stream>>>(indices, num_salt, out);
    }
}

// Round 11
// 78.440 us; speedup vs baseline: 7.9336x; 1.0795x over previous
//
#include <hip/hip_runtime.h>

// Problem constants (from reference)
#define NPIX     786432                     // C*H*W = 3*512*512
#define NSP      55050                      // noise pixels per sample
#define BATCH    64
#define LOG_CHUNK 15
#define CHUNK_PX (1 << LOG_CHUNK)           // 32768 pixels per chunk
#define NCHUNK   (NPIX / CHUNK_PX)          // 24 chunks per sample
#define BINB     16                         // bin blocks per sample
#define CAP_B    224                        // entries per (sample,chunk,binblock)
#define F4_PER_CHUNK (CHUNK_PX / 4)         // 8192 float4
#define MASK_WORDS   (CHUNK_PX / 16)        // 2048 u32 = 8 KB LDS (2 bits/px)
#define PF       8                          // prefetched stream iterations

// ws layout: u32 counts[64][24][16] @ 0 (fully rewritten every call);
//            u16 entries[64][24][16][CAP_B] @ 98304 (11.0 MB)
#define COUNTS_WORDS (BATCH * NCHUNK * BINB)
#define ENTRIES_OFF  (COUNTS_WORDS * 4)
#define WS_NEEDED    (ENTRIES_OFF + (size_t)BATCH * NCHUNK * BINB * CAP_B * 2)

typedef float f32x4 __attribute__((ext_vector_type(4)));
typedef int   i32x2 __attribute__((ext_vector_type(2)));
typedef unsigned int u32;
typedef unsigned short u16;

// Kernel A (unchanged — proven ~5 µs): single-scan bin, 16 blocks/sample,
// int2 NT index loads, LDS atomicAdd compaction, wave-parallel dump to
// dedicated slices. No global atomics, no memset.
__global__ __launch_bounds__(512) void bin_kernel(
    const int* __restrict__ indices, const int* __restrict__ num_salt,
    u32* __restrict__ counts, u16* __restrict__ entries)
{
    __shared__ u16 stage[NCHUNK][CAP_B];
    __shared__ u32 lcnt[NCHUNK];
    const int b  = blockIdx.y;
    const int cb = blockIdx.x;
    const int t  = threadIdx.x;
    const int ns = num_salt[b];

    if (t < NCHUNK) lcnt[t] = 0;
    __syncthreads();

    const i32x2* __restrict__ ind2 = (const i32x2*)(indices + b * NSP);
    const int M = NSP / 2;                   // 27525 int2s (exact)
    for (int m = cb * 512 + t; m < M; m += BINB * 512) {
        i32x2 p2 = __builtin_nontemporal_load(ind2 + m);
        #pragma unroll
        for (int h = 0; h < 2; ++h) {
            int p = p2[h];
            int j = 2 * m + h;
            int q = p >> LOG_CHUNK;
            u32 r = atomicAdd(&lcnt[q], 1u);
            u16 e = (u16)((p & (CHUNK_PX - 1)) | ((j < ns) ? 0x8000u : 0u));
            if (r < CAP_B) stage[q][r] = e;
        }
    }
    __syncthreads();

    const int w = t >> 6, lane = t & 63;
    for (int q = w; q < NCHUNK; q += 8) {
        u32 c = lcnt[q]; if (c > CAP_B) c = CAP_B;
        if (lane == 0) counts[(b * NCHUNK + q) * BINB + cb] = c;
        u16* __restrict__ dst = entries + ((size_t)(b * NCHUNK + q) * BINB + cb) * CAP_B;
        for (u32 e = lane; e < c; e += 64) dst[e] = stage[q][e];
    }
}

#define DECODE_STORE(v, i)                                                     \
    {                                                                          \
        u32 m = (smask[(i) >> 2] >> (((i) & 3) * 8)) & 0xFFu;                  \
        f32x4 o;                                                               \
        o.x = (m & 1u)  ? (float)((m >> 1) & 1u) : fminf(fmaxf(v.x, 0.f), 1.f);\
        o.y = (m & 4u)  ? (float)((m >> 3) & 1u) : fminf(fmaxf(v.y, 0.f), 1.f);\
        o.z = (m & 16u) ? (float)((m >> 5) & 1u) : fminf(fmaxf(v.z, 0.f), 1.f);\
        o.w = (m & 64u) ? (float)((m >> 7) & 1u) : fminf(fmaxf(v.w, 0.f), 1.f);\
        op[i] = o;                                                             \
    }

// Kernel B: per 32768-px chunk (512 threads).
//  - PF=8 issue-early: first stream NT loads issued before the mask build.
//  - WAVE-PARALLEL mask build: wave w owns slices {w, w+8}; 16 serial
//    block-wide slice loops become 2 short per-wave loops (~2.3 load iters),
//    count loads are per-wave broadcasts. Disjoint-bit atomicOr keeps the
//    result order-independent -> deterministic.
__global__ __launch_bounds__(512) void apply_kernel(
    const f32x4* __restrict__ in, f32x4* __restrict__ out,
    const u32* __restrict__ counts, const u16* __restrict__ entries)
{
    __shared__ u32 smask[MASK_WORDS];
    const int b = blockIdx.y, q = blockIdx.x, t = threadIdx.x;

    const size_t base4 = (size_t)(b * NCHUNK + q) * F4_PER_CHUNK;
    const f32x4* __restrict__ ip = in + base4;
    f32x4* __restrict__ op = out + base4;

    // --- issue-early: first PF stream loads (independent of the mask) ---
    f32x4 pf[PF];
    #pragma unroll
    for (int k = 0; k < PF; ++k)
        pf[k] = __builtin_nontemporal_load(ip + k * 512 + t);

    // --- mask zero + wave-parallel build ---
    #pragma unroll
    for (int w = t; w < MASK_WORDS; w += 512) smask[w] = 0u;
    __syncthreads();

    const u32* __restrict__ cp = counts + (b * NCHUNK + q) * BINB;
    const u16* __restrict__ ep = entries + (size_t)(b * NCHUNK + q) * BINB * CAP_B;
    const int w = t >> 6, lane = t & 63;
    #pragma unroll
    for (int s = 0; s < 2; ++s) {
        const int cb = w + s * 8;
        u32 cnt = cp[cb];                      // same addr across wave -> broadcast
        const u16* __restrict__ sl = ep + cb * CAP_B;
        for (u32 e = lane; e < cnt; e += 64) {
            u32 v = sl[e];
            u32 lp = v & (CHUNK_PX - 1);
            u32 bits = (1u | ((v >> 15) << 1)) << ((lp & 15) * 2);
            atomicOr(&smask[lp >> 4], bits);
        }
    }
    __syncthreads();

    // --- drain prefetched iterations ---
    #pragma unroll
    for (int k = 0; k < PF; ++k)
        DECODE_STORE(pf[k], k * 512 + t)

    // --- remaining stream iterations ---
    #pragma unroll
    for (int kk = PF; kk < F4_PER_CHUNK / 512; ++kk) {
        int i = kk * 512 + t;
        f32x4 v = __builtin_nontemporal_load(ip + i);
        DECODE_STORE(v, i)
    }
}

// ---- fallback (ws too small): proven round-2/4 two-pass path ----
__global__ __launch_bounds__(256) void copy_clip_kernel(
    const f32x4* __restrict__ in, f32x4* __restrict__ out, int n4) {
    int stride = gridDim.x * blockDim.x;
    for (int i = blockIdx.x * blockDim.x + threadIdx.x; i < n4; i += stride) {
        f32x4 v = __builtin_nontemporal_load(in + i);
        v.x = fminf(fmaxf(v.x, 0.f), 1.f); v.y = fminf(fmaxf(v.y, 0.f), 1.f);
        v.z = fminf(fmaxf(v.z, 0.f), 1.f); v.w = fminf(fmaxf(v.w, 0.f), 1.f);
        out[i] = v;
    }
}
__global__ __launch_bounds__(256) void scatter_kernel(
    const int* __restrict__ indices, const int* __restrict__ num_salt,
    float* __restrict__ out) {
    int b = blockIdx.y;
    int j = blockIdx.x * blockDim.x + threadIdx.x;
    if (j >= NSP) return;
    out[(size_t)b * NPIX + indices[b * NSP + j]] = (j < num_salt[b]) ? 1.0f : 0.0f;
}

extern "C" void kernel_launch(void* const* d_in, const int* in_sizes, int n_in,
                              void* d_out, int out_size, void* d_ws, size_t ws_size,
                              hipStream_t stream) {
    const float* x        = (const float*)d_in[0];
    const int*   indices  = (const int*)d_in[1];
    const int*   num_salt = (const int*)d_in[2];
    float*       out      = (float*)d_out;

    if (ws_size >= WS_NEEDED) {
        u32* counts  = (u32*)d_ws;
        u16* entries = (u16*)((char*)d_ws + ENTRIES_OFF);
        dim3 agrid(BINB, BATCH);               // (16, 64) x 512 thr
        bin_kernel<<<agrid, 512, 0, stream>>>(indices, num_salt, counts, entries);
        dim3 bgrid(NCHUNK, BATCH);             // (24, 64) x 512 thr
        apply_kernel<<<bgrid, 512, 0, stream>>>(
            (const f32x4*)x, (f32x4*)out, counts, entries);
    } else {
        int n4 = out_size / 4;
        copy_clip_kernel<<<2048, 256, 0, stream>>>((const f32x4*)x, (f32x4*)out, n4);
        dim3 sgrid((NSP + 255) / 256, BATCH);
        scatter_kernel<<<sgrid, 256, 0, stream>>>(indices, num_salt, out);
    }
}